// Round 7
// baseline (185.569 us; speedup 1.0000x reference)
//
#include <hip/hip_runtime.h>

#define CCH   256
#define NSEQ  4096
#define NH    8
#define HD    32

typedef short s8x __attribute__((ext_vector_type(8)));
typedef float f4x __attribute__((ext_vector_type(4)));

__device__ __forceinline__ f4x mfma16(s8x a, s8x b, f4x c) {
  return __builtin_amdgcn_mfma_f32_16x16x32_bf16(a, b, c, 0, 0, 0);
}

__device__ __forceinline__ unsigned short f2bf(float f) {
  union { float f; unsigned int u; } v; v.f = f;
  unsigned int u = v.u + 0x7fffu + ((v.u >> 16) & 1u);
  return (unsigned short)(u >> 16);
}

__device__ __forceinline__ unsigned int pk_bf_rnd(float lo, float hi) {
  return (unsigned int)f2bf(lo) | ((unsigned int)f2bf(hi) << 16);
}

// pack two f32 -> one u32 of bf16 (truncating; P >= 0 so safe)
__device__ __forceinline__ unsigned int pk_bf_trunc(float lo, float hi) {
  union { float f; unsigned int u; } a, b; a.f = lo; b.f = hi;
  return __builtin_amdgcn_perm(b.u, a.u, 0x07060302);
}

// raw v_exp_f32
#if defined(__has_builtin)
#if __has_builtin(__builtin_amdgcn_exp2f)
#define FEXP2(x) __builtin_amdgcn_exp2f(x)
#endif
#endif
#ifndef FEXP2
__device__ __forceinline__ float __fexp2_asm(float x) {
  float r; asm("v_exp_f32 %0, %1" : "=v"(r) : "v"(x)); return r;
}
#define FEXP2(x) __fexp2_asm(x)
#endif

#define C2SCALE (0.17677669529663689f * 1.4426950408889634f)

// ---------------- LayerNorm + transpose, with cvt_weights folded in ----------------
__global__ __launch_bounds__(256) void ln_cvt_kernel(const float* __restrict__ x,
                                                     const float* __restrict__ nw,
                                                     const float* __restrict__ nb,
                                                     unsigned short* __restrict__ xn,
                                                     const float* __restrict__ qw,
                                                     const float* __restrict__ pw,
                                                     unsigned short* __restrict__ qwb,
                                                     unsigned short* __restrict__ pwb) {
  if (blockIdx.x >= 256) {
    const int t = (blockIdx.x - 256) * 256 + threadIdx.x;   // 0..65535
    const float4* src;
    unsigned short* dst;
    int idx;
    if (t < 49152) { src = reinterpret_cast<const float4*>(qw); dst = qwb; idx = t; }
    else           { src = reinterpret_cast<const float4*>(pw); dst = pwb; idx = t - 49152; }
    const float4 vv = src[idx];
    union { unsigned short u[4]; uint2 v; } pk;
    pk.u[0] = f2bf(vv.x); pk.u[1] = f2bf(vv.y); pk.u[2] = f2bf(vv.z); pk.u[3] = f2bf(vv.w);
    *reinterpret_cast<uint2*>(dst + 4 * idx) = pk.v;
    return;
  }

  __shared__ float Ls[256 * 32];
  __shared__ float Sred[2][32][8];
  const int t  = threadIdx.x;
  const int n  = t & 31;
  const int cg = t >> 5;
  const int p0 = blockIdx.x * 32;
  const int b  = p0 >> 12;
  const int n0 = p0 & 4095;
  const float* xb = x + (size_t)b * CCH * NSEQ + n0;

  #pragma unroll
  for (int i = 0; i < 32; ++i) {
    const int c = i * 8 + cg;
    Ls[c * 32 + (n ^ (c & 31))] = xb[(size_t)c * NSEQ + n];
  }
  __syncthreads();

  float s = 0.f, sq = 0.f;
  #pragma unroll
  for (int j = 0; j < 32; ++j) {
    const int c = cg * 32 + j;
    const float v = Ls[c * 32 + (n ^ j)];
    s += v; sq += v * v;
  }
  Sred[0][n][cg] = s; Sred[1][n][cg] = sq;
  __syncthreads();
  float ts = 0.f, tq = 0.f;
  #pragma unroll
  for (int g = 0; g < 8; ++g) { ts += Sred[0][n][g]; tq += Sred[1][n][g]; }
  const float mean = ts * (1.f / 256.f);
  const float rstd = rsqrtf(tq * (1.f / 256.f) - mean * mean + 1e-5f);

  unsigned short* orow = xn + ((size_t)b * NSEQ + n0 + n) * CCH + cg * 32;
  #pragma unroll
  for (int j8 = 0; j8 < 4; ++j8) {
    unsigned int w_[4];
    #pragma unroll
    for (int hw = 0; hw < 4; ++hw) {
      const int j = j8 * 8 + hw * 2;
      const int c = cg * 32 + j;
      const float v0 = Ls[c * 32 + (n ^ j)];
      const float v1 = Ls[(c + 1) * 32 + (n ^ (j + 1))];
      const float y0 = (v0 - mean) * rstd * nw[c] + nb[c];
      const float y1 = (v1 - mean) * rstd * nw[c + 1] + nb[c + 1];
      w_[hw] = pk_bf_rnd(y0, y1);
    }
    uint4 pkv; pkv.x = w_[0]; pkv.y = w_[1]; pkv.z = w_[2]; pkv.w = w_[3];
    *reinterpret_cast<uint4*>(orow + j8 * 8) = pkv;
  }
}

// ======== shared LDS-tiled GEMM core: 128m x 64n tile, BK=64, K=256 ========
#define GEMM_CORE(A_PTR, B_PTR, ACC)                                            \
  {                                                                             \
    for (int kb = 0; kb < 4; ++kb) {                                            \
      if (kb) __syncthreads();                                                  \
      _Pragma("unroll")                                                         \
      for (int j = 0; j < 4; ++j) {                                             \
        const int c = j * 256 + tid;                                            \
        const int ar = c >> 3, acr = c & 7;                                     \
        *reinterpret_cast<s8x*>(&As[ar * 64 + ((acr ^ (ar & 7)) << 3)]) =       \
          *reinterpret_cast<const s8x*>(A_PTR + (size_t)(mt * 128 + ar) * CCH + kb * 64 + acr * 8); \
      }                                                                         \
      _Pragma("unroll")                                                         \
      for (int j = 0; j < 2; ++j) {                                             \
        const int c = j * 256 + tid;                                            \
        const int br = c >> 3, bcr = c & 7;                                     \
        *reinterpret_cast<s8x*>(&Bs[br * 64 + ((bcr ^ (br & 7)) << 3)]) =       \
          *reinterpret_cast<const s8x*>(B_PTR + (size_t)(nt * 64 + br) * CCH + kb * 64 + bcr * 8); \
      }                                                                         \
      __syncthreads();                                                          \
      _Pragma("unroll")                                                         \
      for (int kin = 0; kin < 2; ++kin) {                                       \
        const int chx = ((kin * 4 + quad) ^ (l16 & 7)) << 3;                    \
        const s8x a0 = *reinterpret_cast<const s8x*>(&As[(wv * 32 + l16) * 64 + chx]);      \
        const s8x a1 = *reinterpret_cast<const s8x*>(&As[(wv * 32 + 16 + l16) * 64 + chx]); \
        _Pragma("unroll")                                                       \
        for (int ni = 0; ni < 4; ++ni) {                                        \
          const s8x bf = *reinterpret_cast<const s8x*>(&Bs[(ni * 16 + l16) * 64 + chx]);    \
          ACC[0][ni] = mfma16(a0, bf, ACC[0][ni]);                              \
          ACC[1][ni] = mfma16(a1, bf, ACC[1][ni]);                              \
        }                                                                       \
      }                                                                         \
    }                                                                           \
  }

// ---------------- QKV GEMM (tiled, LDS-transposed epilogue) ----------------
// grid (64, 12).  Epilogue: acc -> Es[c][n] (stride 136 shorts, bank-clean),
// then coalesced uint4 stores: q/k as (B,NH,N,HD) rows, v as (B,NH,HD,N) rows.
__global__ __launch_bounds__(256, 3) void qkv_gemm(const unsigned short* __restrict__ xn,
                                                   const unsigned short* __restrict__ w,
                                                   const float* __restrict__ bias,
                                                   unsigned short* __restrict__ q,
                                                   unsigned short* __restrict__ k,
                                                   unsigned short* __restrict__ vt) {
  __shared__ char pool[24576];   // As 16K + Bs 8K; Es (17408) overlays after barrier
  unsigned short* As = (unsigned short*)pool;
  unsigned short* Bs = (unsigned short*)(pool + 16384);
  unsigned short* Es = (unsigned short*)pool;

  const int tid = threadIdx.x;
  const int wv  = tid >> 6;
  const int lane = tid & 63;
  const int quad = lane >> 4, l16 = lane & 15;
  const int mt = blockIdx.x;
  const int nt = blockIdx.y;

  f4x acc[2][4];
  #pragma unroll
  for (int mi = 0; mi < 2; ++mi)
    #pragma unroll
    for (int ni = 0; ni < 4; ++ni)
      acc[mi][ni] = (f4x){0.f, 0.f, 0.f, 0.f};

  GEMM_CORE(xn, w, acc)

  const int sel = nt >> 2;                  // 0=q 1=k 2=v
  const float sc = (sel == 0) ? C2SCALE : 1.f;

  __syncthreads();   // staging reads done before Es overlay
  #pragma unroll
  for (int ni = 0; ni < 4; ++ni) {
    const float bs = bias[nt * 64 + ni * 16 + l16];
    #pragma unroll
    for (int mi = 0; mi < 2; ++mi) {
      const int nl = wv * 32 + mi * 16 + quad * 4;
      uint2 pk;
      pk.x = pk_bf_rnd((acc[mi][ni][0] + bs) * sc, (acc[mi][ni][1] + bs) * sc);
      pk.y = pk_bf_rnd((acc[mi][ni][2] + bs) * sc, (acc[mi][ni][3] + bs) * sc);
      *reinterpret_cast<uint2*>(&Es[(ni * 16 + l16) * 136 + nl]) = pk;
    }
  }
  __syncthreads();

  if (sel < 2) {
    // (B,NH,N,HD): thread -> one (head,n) row of 32 d = 64 B
    unsigned short* base = (sel == 0) ? q : k;
    const int hl = tid >> 7;          // local head 0..1
    const int nl = tid & 127;
    const int g0 = mt * 128 + nl;
    const int bb = g0 >> 12, n = g0 & 4095;
    const int head = ((nt & 3) << 1) + hl;
    unsigned short* dst = base + ((size_t)(bb * NH + head) * NSEQ + n) * HD;
    unsigned int w_[16];
    #pragma unroll
    for (int d2 = 0; d2 < 16; ++d2) {
      const unsigned int lo = Es[(hl * 32 + 2 * d2) * 136 + nl];
      const unsigned int hi = Es[(hl * 32 + 2 * d2 + 1) * 136 + nl];
      w_[d2] = lo | (hi << 16);
    }
    #pragma unroll
    for (int j4 = 0; j4 < 4; ++j4) {
      uint4 pkv;
      pkv.x = w_[j4 * 4]; pkv.y = w_[j4 * 4 + 1];
      pkv.z = w_[j4 * 4 + 2]; pkv.w = w_[j4 * 4 + 3];
      *reinterpret_cast<uint4*>(dst + j4 * 8) = pkv;
    }
  } else {
    // (B,NH,HD,N): thread -> (c=d-row, 32-n chunk)
    const int c = tid >> 2, j = tid & 3;
    const int head = ((nt - 8) << 1) + (c >> 5), d = c & 31;
    const int g0 = mt * 128 + j * 32;
    const int bb = g0 >> 12, n = g0 & 4095;
    unsigned short* dst = vt + ((size_t)(bb * NH + head) * HD + d) * NSEQ + n;
    #pragma unroll
    for (int kk = 0; kk < 4; ++kk) {
      const uint4 vv = *reinterpret_cast<const uint4*>(&Es[c * 136 + j * 32 + kk * 8]);
      *reinterpret_cast<uint4*>(dst + kk * 8) = vv;
    }
  }
}

// ---------------- proj GEMM + residual (tiled, f32 LDS epilogue) ----------------
// grid (64, 4).  Ef[c][n] f32 stride 132 (bank-clean); bias+gamma+residual in the
// read phase where x-read and out-store are coalesced along n.
__global__ __launch_bounds__(256, 3) void proj_gemm(const unsigned short* __restrict__ xa,
                                                    const unsigned short* __restrict__ w,
                                                    const float* __restrict__ bias,
                                                    const float* __restrict__ gamma,
                                                    const float* __restrict__ x,
                                                    float* __restrict__ out) {
  __shared__ char pool[33792];   // max(As+Bs = 24576, Ef = 33792)
  unsigned short* As = (unsigned short*)pool;
  unsigned short* Bs = (unsigned short*)(pool + 16384);
  float* Ef = (float*)pool;

  const int tid = threadIdx.x;
  const int wv  = tid >> 6;
  const int lane = tid & 63;
  const int quad = lane >> 4, l16 = lane & 15;
  const int mt = blockIdx.x;
  const int nt = blockIdx.y;

  f4x acc[2][4];
  #pragma unroll
  for (int mi = 0; mi < 2; ++mi)
    #pragma unroll
    for (int ni = 0; ni < 4; ++ni)
      acc[mi][ni] = (f4x){0.f, 0.f, 0.f, 0.f};

  GEMM_CORE(xa, w, acc)

  __syncthreads();
  #pragma unroll
  for (int ni = 0; ni < 4; ++ni)
    #pragma unroll
    for (int mi = 0; mi < 2; ++mi) {
      const int nl = wv * 32 + mi * 16 + quad * 4;
      *reinterpret_cast<f4x*>(&Ef[(ni * 16 + l16) * 132 + nl]) = acc[mi][ni];
    }
  __syncthreads();

  const float gm = gamma[0];
  const int c = tid >> 2, j = tid & 3;
  const int ch = nt * 64 + c;
  const float bs = bias[ch];
  const int g0 = mt * 128 + j * 32;
  const int bb = g0 >> 12, n0 = g0 & 4095;
  const size_t off = (size_t)(bb * CCH + ch) * NSEQ + n0;
  #pragma unroll
  for (int kk = 0; kk < 8; ++kk) {
    const float4 ev = *reinterpret_cast<const float4*>(&Ef[c * 132 + j * 32 + kk * 4]);
    const float4 xv = *reinterpret_cast<const float4*>(x + off + kk * 4);
    float4 ov;
    ov.x = gm * (ev.x + bs) + xv.x;
    ov.y = gm * (ev.y + bs) + xv.y;
    ov.z = gm * (ev.z + bs) + xv.z;
    ov.w = gm * (ev.w + bs) + xv.w;
    *reinterpret_cast<float4*>(out + off + kk * 4) = ov;
  }
}

// ---------------- Flash attention (software-pipelined, barrier-free) ----------------
// 512 blocks (bh = i&15 -> XCD pinning), 256 thr = 4 waves, wave owns 32 q-cols.
// Ps stride 144 shorts (72 dw = 8 mod 32): b64 writes 4/bank, b128 reads 8/bank
// -- both at theoretical LDS minimum (verified arithmetic; 136 gave 8-way reads).
__global__ __launch_bounds__(256, 2) void fa_kernel(const unsigned short* __restrict__ q,
                                                    const unsigned short* __restrict__ k,
                                                    const unsigned short* __restrict__ vt,
                                                    unsigned short* __restrict__ xa) {
  __shared__ unsigned short Ps[128 * 144];   // 36 KiB

  const int tid  = threadIdx.x;
  const int wv   = tid >> 6;
  const int lane = tid & 63;
  const int quad = lane >> 4;
  const int l16  = lane & 15;
  const int i    = blockIdx.x;
  const int bh   = i & 15;
  const int qblk = i >> 4;
  const int b    = bh >> 3;
  const int h    = bh & 7;

  const unsigned short* kb_ = k  + (size_t)bh * NSEQ * HD;
  const unsigned short* vb_ = vt + (size_t)bh * HD * NSEQ;

  s8x bq0, bq1;
  {
    const unsigned short* qb = q + ((size_t)bh * NSEQ + (size_t)qblk * 128 + wv * 32) * HD;
    bq0 = *reinterpret_cast<const s8x*>(qb + (size_t)l16 * HD + quad * 8);
    bq1 = *reinterpret_cast<const s8x*>(qb + (size_t)(16 + l16) * HD + quad * 8);
  }
  s8x ak[8];
  #pragma unroll
  for (int ii = 0; ii < 8; ++ii)
    ak[ii] = *reinterpret_cast<const s8x*>(kb_ + (size_t)(ii * 16 + l16) * HD + quad * 8);
  s8x av[8];
  #pragma unroll
  for (int kb2 = 0; kb2 < 4; ++kb2) {
    av[kb2]     = *reinterpret_cast<const s8x*>(vb_ + (size_t)l16 * NSEQ + kb2 * 32 + quad * 8);
    av[4 + kb2] = *reinterpret_cast<const s8x*>(vb_ + (size_t)(16 + l16) * NSEQ + kb2 * 32 + quad * 8);
  }

  // S(0), then refill ak with tile 1
  f4x st[8][2];
  #pragma unroll
  for (int ii = 0; ii < 8; ++ii) {
    const f4x z = {0.f, 0.f, 0.f, 0.f};
    st[ii][0] = mfma16(ak[ii], bq0, z);
    st[ii][1] = mfma16(ak[ii], bq1, z);
  }
  #pragma unroll
  for (int ii = 0; ii < 8; ++ii)
    ak[ii] = *reinterpret_cast<const s8x*>(kb_ + (size_t)(128 + ii * 16 + l16) * HD + quad * 8);

  f4x oacc[2][2];
  #pragma unroll
  for (int dt = 0; dt < 2; ++dt)
    #pragma unroll
    for (int ct = 0; ct < 2; ++ct)
      oacc[dt][ct] = (f4x){0.f, 0.f, 0.f, 0.f};
  f4x accL[2] = {(f4x){0.f, 0.f, 0.f, 0.f}, (f4x){0.f, 0.f, 0.f, 0.f}};

  s8x ones;
  #pragma unroll
  for (int j = 0; j < 8; ++j) ones[j] = (short)0x3F80;   // bf16 1.0

  const int r0 = (wv * 32 + l16) * 144;
  const int r1 = (wv * 32 + 16 + l16) * 144;

  for (int it = 0; it < NSEQ / 128; ++it) {
    // ---- exp + pack + write P(it) ----
    #pragma unroll
    for (int ct = 0; ct < 2; ++ct) {
      const int prow = (wv * 32 + ct * 16 + l16) * 144;
      #pragma unroll
      for (int ii = 0; ii < 8; ++ii) {
        const float e0 = FEXP2(st[ii][ct][0]);
        const float e1 = FEXP2(st[ii][ct][1]);
        const float e2 = FEXP2(st[ii][ct][2]);
        const float e3 = FEXP2(st[ii][ct][3]);
        uint2 pw;
        pw.x = pk_bf_trunc(e0, e1);
        pw.y = pk_bf_trunc(e2, e3);
        *reinterpret_cast<uint2*>(&Ps[prow + ii * 16 + quad * 4]) = pw;
      }
    }

    // ---- S(it+1) ----
    if (it + 1 < NSEQ / 128) {
      #pragma unroll
      for (int ii = 0; ii < 8; ++ii) {
        const f4x z = {0.f, 0.f, 0.f, 0.f};
        st[ii][0] = mfma16(ak[ii], bq0, z);
        st[ii][1] = mfma16(ak[ii], bq1, z);
      }
    }
    // ---- prefetch K(it+2) ----
    if (it + 2 < NSEQ / 128) {
      const unsigned short* kn = kb_ + (size_t)(it + 2) * 128 * HD;
      #pragma unroll
      for (int ii = 0; ii < 8; ++ii)
        ak[ii] = *reinterpret_cast<const s8x*>(kn + (size_t)(ii * 16 + l16) * HD + quad * 8);
    }

    // ---- PV(it) + l-accum ----
    #pragma unroll
    for (int kb2 = 0; kb2 < 4; ++kb2) {
      const s8x bp0 = *reinterpret_cast<const s8x*>(&Ps[r0 + kb2 * 32 + quad * 8]);
      const s8x bp1 = *reinterpret_cast<const s8x*>(&Ps[r1 + kb2 * 32 + quad * 8]);
      oacc[0][0] = mfma16(av[kb2],     bp0, oacc[0][0]);
      oacc[1][0] = mfma16(av[4 + kb2], bp0, oacc[1][0]);
      oacc[0][1] = mfma16(av[kb2],     bp1, oacc[0][1]);
      oacc[1][1] = mfma16(av[4 + kb2], bp1, oacc[1][1]);
      accL[0] = mfma16(ones, bp0, accL[0]);
      accL[1] = mfma16(ones, bp1, accL[1]);
    }

    // ---- prefetch V^T(it+1) ----
    if (it + 1 < NSEQ / 128) {
      const unsigned short* vn = vb_ + (size_t)(it + 1) * 128;
      #pragma unroll
      for (int kb2 = 0; kb2 < 4; ++kb2) {
        av[kb2]     = *reinterpret_cast<const s8x*>(vn + (size_t)l16 * NSEQ + kb2 * 32 + quad * 8);
        av[4 + kb2] = *reinterpret_cast<const s8x*>(vn + (size_t)(16 + l16) * NSEQ + kb2 * 32 + quad * 8);
      }
    }
  }

  // ---- epilogue ----
  #pragma unroll
  for (int ct = 0; ct < 2; ++ct) {
    const float il = 1.f / accL[ct][0];
    const int qg = qblk * 128 + wv * 32 + ct * 16 + l16;
    #pragma unroll
    for (int dt = 0; dt < 2; ++dt) {
      uint2 ow;
      ow.x = pk_bf_rnd(oacc[dt][ct][0] * il, oacc[dt][ct][1] * il);
      ow.y = pk_bf_rnd(oacc[dt][ct][2] * il, oacc[dt][ct][3] * il);
      unsigned short* dst = xa + ((size_t)b * NSEQ + qg) * CCH + h * HD + dt * 16 + quad * 4;
      *reinterpret_cast<uint2*>(dst) = ow;
    }
  }
}

extern "C" void kernel_launch(void* const* d_in, const int* in_sizes, int n_in,
                              void* d_out, int out_size, void* d_ws, size_t ws_size,
                              hipStream_t stream) {
  const float* x      = (const float*)d_in[0];
  const float* norm_w = (const float*)d_in[1];
  const float* norm_b = (const float*)d_in[2];
  const float* qkv_w  = (const float*)d_in[3];
  const float* qkv_b  = (const float*)d_in[4];
  const float* proj_w = (const float*)d_in[5];
  const float* proj_b = (const float*)d_in[6];
  const float* gamma  = (const float*)d_in[7];
  float* out = (float*)d_out;

  char* ws = (char*)d_ws;
  unsigned short* xn  = (unsigned short*)(ws);              // (B,N,C) bf16, 4 MiB
  unsigned short* qwb = (unsigned short*)(ws + 4194304);
  unsigned short* pwb = (unsigned short*)(ws + 4587520);
  unsigned short* q   = (unsigned short*)(ws + 4718592);    // (B,NH,N,HD), pre-scaled
  unsigned short* k   = (unsigned short*)(ws + 8912896);    // (B,NH,N,HD)
  unsigned short* vt  = (unsigned short*)(ws + 13107200);   // (B,NH,HD,N)
  unsigned short* xa  = (unsigned short*)(ws + 17301504);   // (B,N,C)

  hipLaunchKernelGGL(ln_cvt_kernel, dim3(512), dim3(256), 0, stream,
                     x, norm_w, norm_b, xn, qkv_w, proj_w, qwb, pwb);
  hipLaunchKernelGGL(qkv_gemm,  dim3(64, 12), dim3(256), 0, stream, xn, qwb, qkv_b, q, k, vt);
  hipLaunchKernelGGL(fa_kernel, dim3(512), dim3(256), 0, stream, q, k, vt, xa);
  hipLaunchKernelGGL(proj_gemm, dim3(64, 4), dim3(256), 0, stream, xa, pwb, proj_b, gamma, x, out);
}